// Round 15
// baseline (100.451 us; speedup 1.0000x reference)
//
#include <hip/hip_runtime.h>
#include <hip/hip_bf16.h>

#define SL     32768
#define EPS_LN 1e-5f

typedef unsigned short u16;
typedef __attribute__((ext_vector_type(8))) short bf16x8;
typedef __attribute__((ext_vector_type(4))) float f32x4;

#define MFMA16(a, b, c) __builtin_amdgcn_mfma_f32_16x16x32_bf16((a), (b), (c), 0, 0, 0)

__device__ inline u16 f2bf(float f) {
    __hip_bfloat16 h = __float2bfloat16(f);
    return *reinterpret_cast<u16*>(&h);
}
__device__ inline float bf2f(u16 u) {
    unsigned v = ((unsigned)u) << 16;
    float f;
    __builtin_memcpy(&f, &v, 4);
    return f;
}
__device__ inline uint4 pack8(float4 a, float4 b) {
    union { uint4 v; u16 u[8]; } U;
    U.u[0] = f2bf(a.x); U.u[1] = f2bf(a.y); U.u[2] = f2bf(a.z); U.u[3] = f2bf(a.w);
    U.u[4] = f2bf(b.x); U.u[5] = f2bf(b.y); U.u[6] = f2bf(b.z); U.u[7] = f2bf(b.w);
    return U.v;
}

// ---------------------------------------------------------------------------
// wcast: w_row, w_col -> bf16 once.
// ---------------------------------------------------------------------------
__global__ __launch_bounds__(256) void wcast_kernel(const float* __restrict__ wr,
                                                    const float* __restrict__ wc,
                                                    u16* __restrict__ wrb,
                                                    u16* __restrict__ wcb) {
    const int i = blockIdx.x * 256 + threadIdx.x;
    const int NW = 384 * 128 / 8;   // 6144
    const float* src = (i < NW) ? wr : wc;
    u16* dst = (i < NW) ? wrb : wcb;
    const int j = (i < NW) ? i : i - NW;
    float4 a = ((const float4*)src)[j * 2];
    float4 b = ((const float4*)src)[j * 2 + 1];
    ((uint4*)dst)[j] = pack8(a, b);
}

// ---------------------------------------------------------------------------
// Pass-1 QKV (round-13 verified). grid 512 n-tiles(64), block 512 (8 waves).
// Input fp32 d-major. q -> qT[h][n][32], k -> kT[h][n][32], v -> vb[c][n].
// ---------------------------------------------------------------------------
__global__ __launch_bounds__(512) void qkv_mfma(const float* __restrict__ in,
                                                const u16* __restrict__ wb,
                                                const float* __restrict__ bq,
                                                u16* __restrict__ qT,
                                                u16* __restrict__ kT,
                                                u16* __restrict__ vb) {
    __shared__ u16 xT[64][136];
    __shared__ float bs[384];
    const int n0 = blockIdx.x * 64;
    const int t = threadIdx.x;
    const int lane = t & 63, wv = t >> 6, lo = lane & 15, hi = lane >> 4;

    if (t < 384) bs[t] = bq[t];

    #pragma unroll
    for (int itr = 0; itr < 2; ++itr) {
        const int u = t + itr * 512;
        const int d = u & 127, noct = u >> 7;
        const float* src = in + (size_t)d * SL + n0 + noct * 8;
        float4 f0 = *(const float4*)src;
        float4 f1 = *(const float4*)(src + 4);
        xT[noct * 8 + 0][d] = f2bf(f0.x);
        xT[noct * 8 + 1][d] = f2bf(f0.y);
        xT[noct * 8 + 2][d] = f2bf(f0.z);
        xT[noct * 8 + 3][d] = f2bf(f0.w);
        xT[noct * 8 + 4][d] = f2bf(f1.x);
        xT[noct * 8 + 5][d] = f2bf(f1.y);
        xT[noct * 8 + 6][d] = f2bf(f1.z);
        xT[noct * 8 + 7][d] = f2bf(f1.w);
    }
    __syncthreads();

    bf16x8 af[3][4];
    #pragma unroll
    for (int om = 0; om < 3; ++om)
        #pragma unroll
        for (int ks = 0; ks < 4; ++ks)
            af[om][ks] = *(const bf16x8*)(wb + (size_t)(wv * 48 + om * 16 + lo) * 128
                                             + hi * 8 + ks * 32);

    #pragma unroll
    for (int nt = 0; nt < 4; ++nt) {
        const int n = n0 + nt * 16 + lo;
        bf16x8 bfr[4];
        #pragma unroll
        for (int ks = 0; ks < 4; ++ks)
            bfr[ks] = *(const bf16x8*)&xT[nt * 16 + lo][hi * 8 + ks * 32];
        #pragma unroll
        for (int om = 0; om < 3; ++om) {
            const int obase = wv * 48 + om * 16;
            f32x4 acc = {0.f, 0.f, 0.f, 0.f};
            #pragma unroll
            for (int ks = 0; ks < 4; ++ks)
                acc = MFMA16(af[om][ks], bfr[ks], acc);
            if (obase < 256) {
                u16* tbuf = (obase < 128) ? qT : kT;
                const int ob = obase & 127;
                const int h = ob >> 5;
                const int cb = (ob & 31) + hi * 4;
                ushort4 o4;
                o4.x = f2bf(acc[0] + bs[obase + hi * 4 + 0]);
                o4.y = f2bf(acc[1] + bs[obase + hi * 4 + 1]);
                o4.z = f2bf(acc[2] + bs[obase + hi * 4 + 2]);
                o4.w = f2bf(acc[3] + bs[obase + hi * 4 + 3]);
                *(ushort4*)(tbuf + (size_t)h * SL * 32 + (size_t)n * 32 + cb) = o4;
            } else {
                const int orow = obase - 256 + hi * 4;
                #pragma unroll
                for (int r = 0; r < 4; ++r)
                    vb[(size_t)(orow + r) * SL + n] = f2bf(acc[r] + bs[obase + hi * 4 + r]);
            }
        }
    }
}

// ---------------------------------------------------------------------------
// Pass-1 attention (round-10/13 verified). Block per (h,outer), wave = 32 q.
// ---------------------------------------------------------------------------
template<int KLEN, int NTHR>
__global__ __launch_bounds__(NTHR) void attn_kernel(const u16* __restrict__ qT,
                                                    const u16* __restrict__ kT,
                                                    const u16* __restrict__ vb,
                                                    u16* __restrict__ ao) {
    constexpr int NJT = KLEN / 16;
    constexpr int NW = NTHR / 64;
    constexpr int NOUT = SL / KLEN;
    __shared__ u16 PT[NW][2][16][36];

    const int bid = blockIdx.x;
    const int outer = bid % NOUT;
    const int h = bid / NOUT;
    const int base = outer * KLEN;
    const int t = threadIdx.x;
    const int lane = t & 63, wv = t >> 6, lo = lane & 15, hi = lane >> 4;
    const int i0w = wv * 32;

    const u16* qh = qT + (size_t)h * SL * 32;
    const u16* kh = kT + (size_t)h * SL * 32;
    const u16* vh = vb + (size_t)h * 32 * SL;

    bf16x8 qf0 = *(const bf16x8*)(qh + (size_t)(base + i0w + lo) * 32 + hi * 8);
    bf16x8 qf1 = *(const bf16x8*)(qh + (size_t)(base + i0w + 16 + lo) * 32 + hi * 8);

    f32x4 o00 = {0.f, 0.f, 0.f, 0.f}, o01 = {0.f, 0.f, 0.f, 0.f};
    f32x4 o10 = {0.f, 0.f, 0.f, 0.f}, o11 = {0.f, 0.f, 0.f, 0.f};
    float ls0[4] = {0.f, 0.f, 0.f, 0.f};
    float ls1[4] = {0.f, 0.f, 0.f, 0.f};

    #pragma unroll
    for (int jt = 0; jt < NJT; ++jt) {
        bf16x8 kf = *(const bf16x8*)(kh + (size_t)(base + jt * 16 + lo) * 32 + hi * 8);
        f32x4 z = {0.f, 0.f, 0.f, 0.f};
        f32x4 s0 = MFMA16(qf0, kf, z);
        f32x4 s1 = MFMA16(qf1, kf, z);
        #pragma unroll
        for (int r = 0; r < 4; ++r) {
            float p0 = __expf(s0[r]);
            ls0[r] += p0;
            PT[wv][0][hi * 4 + r][(jt & 1) * 16 + lo] = f2bf(p0);
            float p1 = __expf(s1[r]);
            ls1[r] += p1;
            PT[wv][1][hi * 4 + r][(jt & 1) * 16 + lo] = f2bf(p1);
        }
        if (jt & 1) {
            const int jb = (jt - 1) * 16;
            bf16x8 pf0 = *(const bf16x8*)&PT[wv][0][lo][hi * 8];
            bf16x8 pf1 = *(const bf16x8*)&PT[wv][1][lo][hi * 8];
            bf16x8 v0 = *(const bf16x8*)(vh + (size_t)lo * SL + base + jb + hi * 8);
            bf16x8 v1 = *(const bf16x8*)(vh + (size_t)(16 + lo) * SL + base + jb + hi * 8);
            o00 = MFMA16(pf0, v0, o00);
            o01 = MFMA16(pf0, v1, o01);
            o10 = MFMA16(pf1, v0, o10);
            o11 = MFMA16(pf1, v1, o11);
        }
    }
    #pragma unroll
    for (int r = 0; r < 4; ++r) {
        float v0 = ls0[r];
        v0 += __shfl_xor(v0, 1);
        v0 += __shfl_xor(v0, 2);
        v0 += __shfl_xor(v0, 4);
        v0 += __shfl_xor(v0, 8);
        ls0[r] = 1.f / v0;
        float v1 = ls1[r];
        v1 += __shfl_xor(v1, 1);
        v1 += __shfl_xor(v1, 2);
        v1 += __shfl_xor(v1, 4);
        v1 += __shfl_xor(v1, 8);
        ls1[r] = 1.f / v1;
    }
    {
        ushort4 o4;
        o4.x = f2bf(o00[0] * ls0[0]);
        o4.y = f2bf(o00[1] * ls0[1]);
        o4.z = f2bf(o00[2] * ls0[2]);
        o4.w = f2bf(o00[3] * ls0[3]);
        *(ushort4*)(ao + (size_t)(h * 32 + lo) * SL + base + i0w + hi * 4) = o4;
        o4.x = f2bf(o01[0] * ls0[0]);
        o4.y = f2bf(o01[1] * ls0[1]);
        o4.z = f2bf(o01[2] * ls0[2]);
        o4.w = f2bf(o01[3] * ls0[3]);
        *(ushort4*)(ao + (size_t)(h * 32 + 16 + lo) * SL + base + i0w + hi * 4) = o4;
        o4.x = f2bf(o10[0] * ls1[0]);
        o4.y = f2bf(o10[1] * ls1[1]);
        o4.z = f2bf(o10[2] * ls1[2]);
        o4.w = f2bf(o10[3] * ls1[3]);
        *(ushort4*)(ao + (size_t)(h * 32 + lo) * SL + base + i0w + 16 + hi * 4) = o4;
        o4.x = f2bf(o11[0] * ls1[0]);
        o4.y = f2bf(o11[1] * ls1[1]);
        o4.z = f2bf(o11[2] * ls1[2]);
        o4.w = f2bf(o11[3] * ls1[3]);
        *(ushort4*)(ao + (size_t)(h * 32 + 16 + lo) * SL + base + i0w + 16 + hi * 4) = o4;
    }
}

// ---------------------------------------------------------------------------
// FUSED pass 2 v2: per-(l,head) blocks. grid 1024 (bid: l = bid>>2, h = bid&3),
// block 384 (6 waves), LDS ~72.7KB -> 2 blocks/CU.
// QKV phase: wave w -> ONE 16-row W tile, global row = (w>>1)*128 + h*32
// + (w&1)*16 + lo  (w 0-1: q, 2-3: k, 4-5: v of head h).
// Attention phase: waves 0-3 -> 32 queries each (128 total).
// ---------------------------------------------------------------------------
__global__ __launch_bounds__(384) void qkv_attn2(const u16* __restrict__ in,   // o1b [p'][128]
                                                 const u16* __restrict__ wb,   // wcb
                                                 const float* __restrict__ bq, // b_col
                                                 u16* __restrict__ ao) {
    __shared__ u16 xS[128][136];        // input column; oS[32][136] overlays later
    __shared__ u16 qkS[2][128][36];     // [q/k][n][c pad36]
    __shared__ u16 vS[32][136];         // [c][n pad136]
    __shared__ u16 PT[4][2][16][36];
    __shared__ float bs[96];

    const int bid = blockIdx.x;
    const int l = bid >> 2;
    const int h = bid & 3;
    const size_t p0 = (size_t)l * 128;
    const int t = threadIdx.x;
    const int lane = t & 63, wv = t >> 6, lo = lane & 15, hi = lane >> 4;

    if (t < 96) bs[t] = bq[(t >> 5) * 128 + h * 32 + (t & 31)];
    // stage input column: 128 rows x 16 uint4 = 2048 units
    for (int idx = t; idx < 2048; idx += 384) {
        const int n = idx >> 4, seg = idx & 15;
        *(uint4*)&xS[n][seg * 8] = *(const uint4*)(in + (p0 + n) * 128 + seg * 8);
    }

    // A-fragments: wave w's 16 W rows (no barrier needed; from global)
    const int grow = (wv >> 1) * 128 + h * 32 + (wv & 1) * 16 + lo;
    bf16x8 af[4];
    #pragma unroll
    for (int ks = 0; ks < 4; ++ks)
        af[ks] = *(const bf16x8*)(wb + (size_t)grow * 128 + hi * 8 + ks * 32);
    __syncthreads();

    // ---- QKV phase: 8 n-tiles x 1 row-tile per wave ----
    #pragma unroll
    for (int nt = 0; nt < 8; ++nt) {
        const int n = nt * 16 + lo;
        bf16x8 bfr[4];
        #pragma unroll
        for (int ks = 0; ks < 4; ++ks)
            bfr[ks] = *(const bf16x8*)&xS[n][hi * 8 + ks * 32];
        f32x4 acc = {0.f, 0.f, 0.f, 0.f};
        #pragma unroll
        for (int ks = 0; ks < 4; ++ks)
            acc = MFMA16(af[ks], bfr[ks], acc);
        const int jb = wv * 16 + hi * 4;          // local row base (bias idx)
        if (wv < 4) {                             // q or k -> qkS[qk][n][c]
            ushort4 o4;
            o4.x = f2bf(acc[0] + bs[jb + 0]);
            o4.y = f2bf(acc[1] + bs[jb + 1]);
            o4.z = f2bf(acc[2] + bs[jb + 2]);
            o4.w = f2bf(acc[3] + bs[jb + 3]);
            *(ushort4*)&qkS[wv >> 1][n][(wv & 1) * 16 + hi * 4] = o4;
        } else {                                  // v -> vS[c][n]
            #pragma unroll
            for (int r = 0; r < 4; ++r)
                vS[(wv & 1) * 16 + hi * 4 + r][n] = f2bf(acc[r] + bs[jb + r]);
        }
    }
    __syncthreads();

    // ---- attention phase: waves 0-3, 32 queries each ----
    u16 (*oS)[136] = xS;   // overlay: xS dead after qkv phase
    if (wv < 4) {
        const int i0w = wv * 32;
        bf16x8 qf0 = *(const bf16x8*)&qkS[0][i0w + lo][hi * 8];
        bf16x8 qf1 = *(const bf16x8*)&qkS[0][i0w + 16 + lo][hi * 8];

        f32x4 o00 = {0.f, 0.f, 0.f, 0.f}, o01 = {0.f, 0.f, 0.f, 0.f};
        f32x4 o10 = {0.f, 0.f, 0.f, 0.f}, o11 = {0.f, 0.f, 0.f, 0.f};
        float ls0[4] = {0.f, 0.f, 0.f, 0.f};
        float ls1[4] = {0.f, 0.f, 0.f, 0.f};

        #pragma unroll
        for (int jt = 0; jt < 8; ++jt) {
            bf16x8 kf = *(const bf16x8*)&qkS[1][jt * 16 + lo][hi * 8];
            f32x4 z = {0.f, 0.f, 0.f, 0.f};
            f32x4 s0 = MFMA16(qf0, kf, z);
            f32x4 s1 = MFMA16(qf1, kf, z);
            #pragma unroll
            for (int r = 0; r < 4; ++r) {
                float pv0 = __expf(s0[r]);
                ls0[r] += pv0;
                PT[wv][0][hi * 4 + r][(jt & 1) * 16 + lo] = f2bf(pv0);
                float pv1 = __expf(s1[r]);
                ls1[r] += pv1;
                PT[wv][1][hi * 4 + r][(jt & 1) * 16 + lo] = f2bf(pv1);
            }
            if (jt & 1) {
                const int jb2 = (jt - 1) * 16;
                bf16x8 pf0 = *(const bf16x8*)&PT[wv][0][lo][hi * 8];
                bf16x8 pf1 = *(const bf16x8*)&PT[wv][1][lo][hi * 8];
                bf16x8 v0 = *(const bf16x8*)&vS[lo][jb2 + hi * 8];
                bf16x8 v1 = *(const bf16x8*)&vS[16 + lo][jb2 + hi * 8];
                o00 = MFMA16(pf0, v0, o00);
                o01 = MFMA16(pf0, v1, o01);
                o10 = MFMA16(pf1, v0, o10);
                o11 = MFMA16(pf1, v1, o11);
            }
        }
        #pragma unroll
        for (int r = 0; r < 4; ++r) {
            float v0 = ls0[r];
            v0 += __shfl_xor(v0, 1);
            v0 += __shfl_xor(v0, 2);
            v0 += __shfl_xor(v0, 4);
            v0 += __shfl_xor(v0, 8);
            ls0[r] = 1.f / v0;
            float v1 = ls1[r];
            v1 += __shfl_xor(v1, 1);
            v1 += __shfl_xor(v1, 2);
            v1 += __shfl_xor(v1, 4);
            v1 += __shfl_xor(v1, 8);
            ls1[r] = 1.f / v1;
        }
        #pragma unroll
        for (int r = 0; r < 4; ++r) {
            oS[lo][i0w + hi * 4 + r]           = f2bf(o00[r] * ls0[r]);
            oS[16 + lo][i0w + hi * 4 + r]      = f2bf(o01[r] * ls0[r]);
            oS[lo][i0w + 16 + hi * 4 + r]      = f2bf(o10[r] * ls1[r]);
            oS[16 + lo][i0w + 16 + hi * 4 + r] = f2bf(o11[r] * ls1[r]);
        }
    }
    __syncthreads();

    // ---- coalesced store: ao[h*32 + ch][p0 + s], 32 ch x 16 segs ----
    for (int idx = t; idx < 512; idx += 384) {
        const int ch = idx >> 4, seg = idx & 15;
        *(uint4*)(ao + (size_t)(h * 32 + ch) * SL + p0 + seg * 8) =
            *(const uint4*)&oS[ch][seg * 8];
    }
}

// ---------------------------------------------------------------------------
// ln_mid (LN1): x fp32 d-major + ao bf16 d-major -> o1b bf16 pos-major.
// ---------------------------------------------------------------------------
__global__ __launch_bounds__(256) void ln_mid(const float* __restrict__ in0,
                                              const u16* __restrict__ in1,
                                              const float* __restrict__ g,
                                              const float* __restrict__ be,
                                              u16* __restrict__ outp) {
    __shared__ float val[128][69];
    __shared__ float redS[4][72];
    __shared__ float redQ[4][72];
    __shared__ float stat[64][2];
    __shared__ float gs[128], bes[128];
    const int bid = blockIdx.x;
    const int r0 = (bid / 16) * 4;
    const int c0 = (bid % 16) * 16;
    const int t = threadIdx.x;
    const int pos = t & 63, q = t >> 6;
    const size_t gp = (size_t)(r0 + (pos >> 4)) * 256 + c0 + (pos & 15);

    if (t < 128) { gs[t] = g[t]; bes[t] = be[t]; }
    float s = 0.f, ss = 0.f;
    #pragma unroll 4
    for (int dd = 0; dd < 32; ++dd) {
        const int d = q * 32 + dd;
        float v = in0[(size_t)d * SL + gp] + bf2f(in1[(size_t)d * SL + gp]);
        val[d][pos] = v;
        s += v; ss += v * v;
    }
    redS[q][pos] = s;
    redQ[q][pos] = ss;
    __syncthreads();
    if (t < 64) {
        const float S  = redS[0][t] + redS[1][t] + redS[2][t] + redS[3][t];
        const float SS = redQ[0][t] + redQ[1][t] + redQ[2][t] + redQ[3][t];
        const float mean = S * (1.f / 128.f);
        const float var  = SS * (1.f / 128.f) - mean * mean;
        stat[t][0] = mean;
        stat[t][1] = rsqrtf(var + EPS_LN);
    }
    __syncthreads();

    {
        const int pr = pos >> 4, pc = pos & 15;
        const size_t pp = (size_t)(c0 + pc) * 128 + r0 + pr;   // p' = l*128+s
        const float mean = stat[pos][0], rstd = stat[pos][1];
        union { uint4 v[4]; u16 u[32]; } O;
        #pragma unroll
        for (int dd = 0; dd < 32; ++dd) {
            const int d = q * 32 + dd;
            O.u[dd] = f2bf((val[d][pos] - mean) * rstd * gs[d] + bes[d]);
        }
        uint4* dst = (uint4*)(outp + pp * 128 + q * 32);
        #pragma unroll
        for (int k = 0; k < 4; ++k) dst[k] = O.v[k];
    }
}

// ---------------------------------------------------------------------------
// ln_out (LN2): o1b pos-major + ao ch-major over p' -> final fp32 d-major.
// ---------------------------------------------------------------------------
__global__ __launch_bounds__(256) void ln_out(const u16* __restrict__ in0,
                                              const u16* __restrict__ in1,
                                              const float* __restrict__ g,
                                              const float* __restrict__ be,
                                              float* __restrict__ outp) {
    __shared__ float val[128][69];
    __shared__ float redS[4][72];
    __shared__ float redQ[4][72];
    __shared__ float stat[64][2];
    const int bid = blockIdx.x;
    const int r0 = (bid / 8) * 4;
    const int c0 = (bid % 8) * 16;
    const int t = threadIdx.x;
    const int pos = t & 63, q = t >> 6;
    const size_t gp = (size_t)(r0 + (pos >> 4)) * 128 + c0 + (pos & 15);

    float s = 0.f, ss = 0.f;
    {
        union { uint4 v[4]; u16 u[32]; } A;
        const uint4* src = (const uint4*)(in0 + gp * 128 + q * 32);
        #pragma unroll
        for (int k = 0; k < 4; ++k) A.v[k] = src[k];
        #pragma unroll 4
        for (int dd = 0; dd < 32; ++dd) {
            const int d = q * 32 + dd;
            float v = bf2f(A.u[dd]) + bf2f(in1[(size_t)d * SL + gp]);
            val[d][pos] = v;
            s += v; ss += v * v;
        }
    }
    redS[q][pos] = s;
    redQ[q][pos] = ss;
    __syncthreads();
    if (t < 64) {
        const float S  = redS[0][t] + redS[1][t] + redS[2][t] + redS[3][t];
        const float SS = redQ[0][t] + redQ[1][t] + redQ[2][t] + redQ[3][t];
        const float mean = S * (1.f / 128.f);
        const float var  = SS * (1.f / 128.f) - mean * mean;
        stat[t][0] = mean;
        stat[t][1] = rsqrtf(var + EPS_LN);
    }
    __syncthreads();

    {
        const int d = t >> 1;
        const int ch = (t & 1) * 8;
        const float gd = g[d], bd = be[d];
        #pragma unroll
        for (int cc = 0; cc < 8; ++cc) {
            const int c = ch + cc;
            float ov[4];
            #pragma unroll
            for (int r = 0; r < 4; ++r) {
                const int p = r * 16 + c;
                ov[r] = (val[d][p] - stat[p][0]) * stat[p][1] * gd + bd;
            }
            float* dst = outp + (size_t)d * SL + (c0 + c) * 256 + r0;
            *(float4*)dst = make_float4(ov[0], ov[1], ov[2], ov[3]);
        }
    }
}

// ---------------------------------------------------------------------------
extern "C" void kernel_launch(void* const* d_in, const int* in_sizes, int n_in,
                              void* d_out, int out_size, void* d_ws, size_t ws_size,
                              hipStream_t stream) {
    const float* x     = (const float*)d_in[0];
    const float* w_row = (const float*)d_in[1];
    const float* b_row = (const float*)d_in[2];
    const float* w_col = (const float*)d_in[3];
    const float* b_col = (const float*)d_in[4];
    const float* g1    = (const float*)d_in[5];
    const float* be1   = (const float*)d_in[6];
    const float* g2    = (const float*)d_in[7];
    const float* be2   = (const float*)d_in[8];
    float* out = (float*)d_out;

    // ws: qT 8MB | kT 8MB | vb 8MB | ao 8MB | o1b 8MB | wrb 96KB | wcb 96KB
    char* base = (char*)d_ws;
    u16* qTb = (u16*)base;                        base += (size_t)128 * SL * 2;
    u16* kTb = (u16*)base;                        base += (size_t)128 * SL * 2;
    u16* vbb = (u16*)base;                        base += (size_t)128 * SL * 2;
    u16* ao16 = (u16*)base;                       base += (size_t)128 * SL * 2;
    u16* o1b  = (u16*)base;                       base += (size_t)128 * SL * 2;
    u16* wrb  = (u16*)base;                       base += (size_t)384 * 128 * 2;
    u16* wcb  = (u16*)base;

    wcast_kernel<<<48, 256, 0, stream>>>(w_row, w_col, wrb, wcb);
    qkv_mfma<<<512, 512, 0, stream>>>(x, wrb, b_row, qTb, kTb, vbb);
    attn_kernel<256, 512><<<512, 512, 0, stream>>>(qTb, kTb, vbb, ao16);
    ln_mid<<<512, 256, 0, stream>>>(x, ao16, g1, be1, o1b);
    qkv_attn2<<<1024, 384, 0, stream>>>(o1b, wcb, b_col, ao16);
    ln_out<<<512, 256, 0, stream>>>(o1b, ao16, g2, be2, out);
}

// Round 16
// 91.448 us; speedup vs baseline: 1.0984x; 1.0984x over previous
//
#include <hip/hip_runtime.h>
#include <hip/hip_bf16.h>

#define SL     32768
#define EPS_LN 1e-5f

typedef unsigned short u16;
typedef __attribute__((ext_vector_type(8))) short bf16x8;
typedef __attribute__((ext_vector_type(4))) float f32x4;

#define MFMA16(a, b, c) __builtin_amdgcn_mfma_f32_16x16x32_bf16((a), (b), (c), 0, 0, 0)

__device__ inline u16 f2bf(float f) {
    __hip_bfloat16 h = __float2bfloat16(f);
    return *reinterpret_cast<u16*>(&h);
}
__device__ inline float bf2f(u16 u) {
    unsigned v = ((unsigned)u) << 16;
    float f;
    __builtin_memcpy(&f, &v, 4);
    return f;
}
__device__ inline uint4 pack8(float4 a, float4 b) {
    union { uint4 v; u16 u[8]; } U;
    U.u[0] = f2bf(a.x); U.u[1] = f2bf(a.y); U.u[2] = f2bf(a.z); U.u[3] = f2bf(a.w);
    U.u[4] = f2bf(b.x); U.u[5] = f2bf(b.y); U.u[6] = f2bf(b.z); U.u[7] = f2bf(b.w);
    return U.v;
}

// ---------------------------------------------------------------------------
// wcast: w_row, w_col -> bf16 once.
// ---------------------------------------------------------------------------
__global__ __launch_bounds__(256) void wcast_kernel(const float* __restrict__ wr,
                                                    const float* __restrict__ wc,
                                                    u16* __restrict__ wrb,
                                                    u16* __restrict__ wcb) {
    const int i = blockIdx.x * 256 + threadIdx.x;
    const int NW = 384 * 128 / 8;   // 6144
    const float* src = (i < NW) ? wr : wc;
    u16* dst = (i < NW) ? wrb : wcb;
    const int j = (i < NW) ? i : i - NW;
    float4 a = ((const float4*)src)[j * 2];
    float4 b = ((const float4*)src)[j * 2 + 1];
    ((uint4*)dst)[j] = pack8(a, b);
}

// ---------------------------------------------------------------------------
// Pass-1 QKV (round-13 verified). grid 512 n-tiles(64), block 512 (8 waves).
// Input fp32 d-major. q -> qT[h][n][32], k -> kT[h][n][32], v -> vb[c][n].
// ---------------------------------------------------------------------------
__global__ __launch_bounds__(512) void qkv_mfma(const float* __restrict__ in,
                                                const u16* __restrict__ wb,
                                                const float* __restrict__ bq,
                                                u16* __restrict__ qT,
                                                u16* __restrict__ kT,
                                                u16* __restrict__ vb) {
    __shared__ u16 xT[64][136];
    __shared__ float bs[384];
    const int n0 = blockIdx.x * 64;
    const int t = threadIdx.x;
    const int lane = t & 63, wv = t >> 6, lo = lane & 15, hi = lane >> 4;

    if (t < 384) bs[t] = bq[t];

    #pragma unroll
    for (int itr = 0; itr < 2; ++itr) {
        const int u = t + itr * 512;
        const int d = u & 127, noct = u >> 7;
        const float* src = in + (size_t)d * SL + n0 + noct * 8;
        float4 f0 = *(const float4*)src;
        float4 f1 = *(const float4*)(src + 4);
        xT[noct * 8 + 0][d] = f2bf(f0.x);
        xT[noct * 8 + 1][d] = f2bf(f0.y);
        xT[noct * 8 + 2][d] = f2bf(f0.z);
        xT[noct * 8 + 3][d] = f2bf(f0.w);
        xT[noct * 8 + 4][d] = f2bf(f1.x);
        xT[noct * 8 + 5][d] = f2bf(f1.y);
        xT[noct * 8 + 6][d] = f2bf(f1.z);
        xT[noct * 8 + 7][d] = f2bf(f1.w);
    }
    __syncthreads();

    bf16x8 af[3][4];
    #pragma unroll
    for (int om = 0; om < 3; ++om)
        #pragma unroll
        for (int ks = 0; ks < 4; ++ks)
            af[om][ks] = *(const bf16x8*)(wb + (size_t)(wv * 48 + om * 16 + lo) * 128
                                             + hi * 8 + ks * 32);

    #pragma unroll
    for (int nt = 0; nt < 4; ++nt) {
        const int n = n0 + nt * 16 + lo;
        bf16x8 bfr[4];
        #pragma unroll
        for (int ks = 0; ks < 4; ++ks)
            bfr[ks] = *(const bf16x8*)&xT[nt * 16 + lo][hi * 8 + ks * 32];
        #pragma unroll
        for (int om = 0; om < 3; ++om) {
            const int obase = wv * 48 + om * 16;
            f32x4 acc = {0.f, 0.f, 0.f, 0.f};
            #pragma unroll
            for (int ks = 0; ks < 4; ++ks)
                acc = MFMA16(af[om][ks], bfr[ks], acc);
            if (obase < 256) {
                u16* tbuf = (obase < 128) ? qT : kT;
                const int ob = obase & 127;
                const int h = ob >> 5;
                const int cb = (ob & 31) + hi * 4;
                ushort4 o4;
                o4.x = f2bf(acc[0] + bs[obase + hi * 4 + 0]);
                o4.y = f2bf(acc[1] + bs[obase + hi * 4 + 1]);
                o4.z = f2bf(acc[2] + bs[obase + hi * 4 + 2]);
                o4.w = f2bf(acc[3] + bs[obase + hi * 4 + 3]);
                *(ushort4*)(tbuf + (size_t)h * SL * 32 + (size_t)n * 32 + cb) = o4;
            } else {
                const int orow = obase - 256 + hi * 4;
                #pragma unroll
                for (int r = 0; r < 4; ++r)
                    vb[(size_t)(orow + r) * SL + n] = f2bf(acc[r] + bs[obase + hi * 4 + r]);
            }
        }
    }
}

// ---------------------------------------------------------------------------
// Pass-1 attention (round-10/13 verified). Block per (h,outer), wave = 32 q.
// ---------------------------------------------------------------------------
template<int KLEN, int NTHR>
__global__ __launch_bounds__(NTHR) void attn_kernel(const u16* __restrict__ qT,
                                                    const u16* __restrict__ kT,
                                                    const u16* __restrict__ vb,
                                                    u16* __restrict__ ao) {
    constexpr int NJT = KLEN / 16;
    constexpr int NW = NTHR / 64;
    constexpr int NOUT = SL / KLEN;
    __shared__ u16 PT[NW][2][16][36];

    const int bid = blockIdx.x;
    const int outer = bid % NOUT;
    const int h = bid / NOUT;
    const int base = outer * KLEN;
    const int t = threadIdx.x;
    const int lane = t & 63, wv = t >> 6, lo = lane & 15, hi = lane >> 4;
    const int i0w = wv * 32;

    const u16* qh = qT + (size_t)h * SL * 32;
    const u16* kh = kT + (size_t)h * SL * 32;
    const u16* vh = vb + (size_t)h * 32 * SL;

    bf16x8 qf0 = *(const bf16x8*)(qh + (size_t)(base + i0w + lo) * 32 + hi * 8);
    bf16x8 qf1 = *(const bf16x8*)(qh + (size_t)(base + i0w + 16 + lo) * 32 + hi * 8);

    f32x4 o00 = {0.f, 0.f, 0.f, 0.f}, o01 = {0.f, 0.f, 0.f, 0.f};
    f32x4 o10 = {0.f, 0.f, 0.f, 0.f}, o11 = {0.f, 0.f, 0.f, 0.f};
    float ls0[4] = {0.f, 0.f, 0.f, 0.f};
    float ls1[4] = {0.f, 0.f, 0.f, 0.f};

    #pragma unroll
    for (int jt = 0; jt < NJT; ++jt) {
        bf16x8 kf = *(const bf16x8*)(kh + (size_t)(base + jt * 16 + lo) * 32 + hi * 8);
        f32x4 z = {0.f, 0.f, 0.f, 0.f};
        f32x4 s0 = MFMA16(qf0, kf, z);
        f32x4 s1 = MFMA16(qf1, kf, z);
        #pragma unroll
        for (int r = 0; r < 4; ++r) {
            float p0 = __expf(s0[r]);
            ls0[r] += p0;
            PT[wv][0][hi * 4 + r][(jt & 1) * 16 + lo] = f2bf(p0);
            float p1 = __expf(s1[r]);
            ls1[r] += p1;
            PT[wv][1][hi * 4 + r][(jt & 1) * 16 + lo] = f2bf(p1);
        }
        if (jt & 1) {
            const int jb = (jt - 1) * 16;
            bf16x8 pf0 = *(const bf16x8*)&PT[wv][0][lo][hi * 8];
            bf16x8 pf1 = *(const bf16x8*)&PT[wv][1][lo][hi * 8];
            bf16x8 v0 = *(const bf16x8*)(vh + (size_t)lo * SL + base + jb + hi * 8);
            bf16x8 v1 = *(const bf16x8*)(vh + (size_t)(16 + lo) * SL + base + jb + hi * 8);
            o00 = MFMA16(pf0, v0, o00);
            o01 = MFMA16(pf0, v1, o01);
            o10 = MFMA16(pf1, v0, o10);
            o11 = MFMA16(pf1, v1, o11);
        }
    }
    #pragma unroll
    for (int r = 0; r < 4; ++r) {
        float v0 = ls0[r];
        v0 += __shfl_xor(v0, 1);
        v0 += __shfl_xor(v0, 2);
        v0 += __shfl_xor(v0, 4);
        v0 += __shfl_xor(v0, 8);
        ls0[r] = 1.f / v0;
        float v1 = ls1[r];
        v1 += __shfl_xor(v1, 1);
        v1 += __shfl_xor(v1, 2);
        v1 += __shfl_xor(v1, 4);
        v1 += __shfl_xor(v1, 8);
        ls1[r] = 1.f / v1;
    }
    {
        ushort4 o4;
        o4.x = f2bf(o00[0] * ls0[0]);
        o4.y = f2bf(o00[1] * ls0[1]);
        o4.z = f2bf(o00[2] * ls0[2]);
        o4.w = f2bf(o00[3] * ls0[3]);
        *(ushort4*)(ao + (size_t)(h * 32 + lo) * SL + base + i0w + hi * 4) = o4;
        o4.x = f2bf(o01[0] * ls0[0]);
        o4.y = f2bf(o01[1] * ls0[1]);
        o4.z = f2bf(o01[2] * ls0[2]);
        o4.w = f2bf(o01[3] * ls0[3]);
        *(ushort4*)(ao + (size_t)(h * 32 + 16 + lo) * SL + base + i0w + hi * 4) = o4;
        o4.x = f2bf(o10[0] * ls1[0]);
        o4.y = f2bf(o10[1] * ls1[1]);
        o4.z = f2bf(o10[2] * ls1[2]);
        o4.w = f2bf(o10[3] * ls1[3]);
        *(ushort4*)(ao + (size_t)(h * 32 + lo) * SL + base + i0w + 16 + hi * 4) = o4;
        o4.x = f2bf(o11[0] * ls1[0]);
        o4.y = f2bf(o11[1] * ls1[1]);
        o4.z = f2bf(o11[2] * ls1[2]);
        o4.w = f2bf(o11[3] * ls1[3]);
        *(ushort4*)(ao + (size_t)(h * 32 + 16 + lo) * SL + base + i0w + 16 + hi * 4) = o4;
    }
}

// ---------------------------------------------------------------------------
// FUSED pass 2 (round-14 verified): qkv2 + col-attention. Block = one l
// (256 blocks, 512 thr, 8 waves, ~160KB LDS -> 1 block/CU).
// ---------------------------------------------------------------------------
__global__ __launch_bounds__(512) void qkv_attn2(const u16* __restrict__ in,   // o1b [p'][128]
                                                 const u16* __restrict__ wb,   // wcb
                                                 const float* __restrict__ bq, // b_col
                                                 u16* __restrict__ ao) {
    __shared__ u16 xS[128][136];             // input rows; oS overlay later
    __shared__ u16 qkS[2][4][128][36];       // [q/k][h][n][c pad36]
    __shared__ u16 vS[4][32][136];           // [h][c][n pad136]
    __shared__ u16 PT[8][2][16][36];
    __shared__ float bs[384];

    const int l = blockIdx.x;
    const size_t p0 = (size_t)l * 128;
    const int t = threadIdx.x;
    const int lane = t & 63, wv = t >> 6, lo = lane & 15, hi = lane >> 4;

    if (t < 384) bs[t] = bq[t];
    #pragma unroll
    for (int itr = 0; itr < 4; ++itr) {
        const int u = t + itr * 512;
        const int n = u >> 4, seg = u & 15;
        *(uint4*)&xS[n][seg * 8] = *(const uint4*)(in + (p0 + n) * 128 + seg * 8);
    }
    __syncthreads();

    // ---- QKV phase: wave w -> o-rows [48w, 48w+48), all 128 n ----
    bf16x8 af[3][4];
    #pragma unroll
    for (int om = 0; om < 3; ++om)
        #pragma unroll
        for (int ks = 0; ks < 4; ++ks)
            af[om][ks] = *(const bf16x8*)(wb + (size_t)(wv * 48 + om * 16 + lo) * 128
                                             + hi * 8 + ks * 32);
    #pragma unroll
    for (int nt = 0; nt < 8; ++nt) {
        const int n = nt * 16 + lo;
        bf16x8 bfr[4];
        #pragma unroll
        for (int ks = 0; ks < 4; ++ks)
            bfr[ks] = *(const bf16x8*)&xS[n][hi * 8 + ks * 32];
        #pragma unroll
        for (int om = 0; om < 3; ++om) {
            const int obase = wv * 48 + om * 16;
            f32x4 acc = {0.f, 0.f, 0.f, 0.f};
            #pragma unroll
            for (int ks = 0; ks < 4; ++ks)
                acc = MFMA16(af[om][ks], bfr[ks], acc);
            if (obase < 256) {
                const int qk = obase >> 7;
                const int ob = obase & 127;
                const int h = ob >> 5;
                const int cb = (ob & 31) + hi * 4;
                ushort4 o4;
                o4.x = f2bf(acc[0] + bs[obase + hi * 4 + 0]);
                o4.y = f2bf(acc[1] + bs[obase + hi * 4 + 1]);
                o4.z = f2bf(acc[2] + bs[obase + hi * 4 + 2]);
                o4.w = f2bf(acc[3] + bs[obase + hi * 4 + 3]);
                *(ushort4*)&qkS[qk][h][n][cb] = o4;
            } else {
                const int vr = obase - 256 + hi * 4;
                #pragma unroll
                for (int r = 0; r < 4; ++r) {
                    const int o = vr + r;
                    vS[o >> 5][o & 31][n] = f2bf(acc[r] + bs[obase + hi * 4 + r]);
                }
            }
        }
    }
    __syncthreads();

    // ---- attention phase: wave w -> head w>>1, queries (w&1)*64 .. +63 ----
    const int h = wv >> 1;
    u16 (*oS)[136] = xS;   // overlay: xS dead after qkv phase

    #pragma unroll
    for (int g = 0; g < 2; ++g) {
        const int ib = (wv & 1) * 64 + g * 32;
        bf16x8 qf0 = *(const bf16x8*)&qkS[0][h][ib + lo][hi * 8];
        bf16x8 qf1 = *(const bf16x8*)&qkS[0][h][ib + 16 + lo][hi * 8];

        f32x4 o00 = {0.f, 0.f, 0.f, 0.f}, o01 = {0.f, 0.f, 0.f, 0.f};
        f32x4 o10 = {0.f, 0.f, 0.f, 0.f}, o11 = {0.f, 0.f, 0.f, 0.f};
        float ls0[4] = {0.f, 0.f, 0.f, 0.f};
        float ls1[4] = {0.f, 0.f, 0.f, 0.f};

        #pragma unroll
        for (int jt = 0; jt < 8; ++jt) {
            bf16x8 kf = *(const bf16x8*)&qkS[1][h][jt * 16 + lo][hi * 8];
            f32x4 z = {0.f, 0.f, 0.f, 0.f};
            f32x4 s0 = MFMA16(qf0, kf, z);
            f32x4 s1 = MFMA16(qf1, kf, z);
            #pragma unroll
            for (int r = 0; r < 4; ++r) {
                float pv0 = __expf(s0[r]);
                ls0[r] += pv0;
                PT[wv][0][hi * 4 + r][(jt & 1) * 16 + lo] = f2bf(pv0);
                float pv1 = __expf(s1[r]);
                ls1[r] += pv1;
                PT[wv][1][hi * 4 + r][(jt & 1) * 16 + lo] = f2bf(pv1);
            }
            if (jt & 1) {
                const int jb = (jt - 1) * 16;
                bf16x8 pf0 = *(const bf16x8*)&PT[wv][0][lo][hi * 8];
                bf16x8 pf1 = *(const bf16x8*)&PT[wv][1][lo][hi * 8];
                bf16x8 v0 = *(const bf16x8*)&vS[h][lo][jb + hi * 8];
                bf16x8 v1 = *(const bf16x8*)&vS[h][16 + lo][jb + hi * 8];
                o00 = MFMA16(pf0, v0, o00);
                o01 = MFMA16(pf0, v1, o01);
                o10 = MFMA16(pf1, v0, o10);
                o11 = MFMA16(pf1, v1, o11);
            }
        }
        #pragma unroll
        for (int r = 0; r < 4; ++r) {
            float v0 = ls0[r];
            v0 += __shfl_xor(v0, 1);
            v0 += __shfl_xor(v0, 2);
            v0 += __shfl_xor(v0, 4);
            v0 += __shfl_xor(v0, 8);
            ls0[r] = 1.f / v0;
            float v1 = ls1[r];
            v1 += __shfl_xor(v1, 1);
            v1 += __shfl_xor(v1, 2);
            v1 += __shfl_xor(v1, 4);
            v1 += __shfl_xor(v1, 8);
            ls1[r] = 1.f / v1;
        }
        #pragma unroll
        for (int r = 0; r < 4; ++r) {
            oS[h * 32 + lo][ib + hi * 4 + r]           = f2bf(o00[r] * ls0[r]);
            oS[h * 32 + 16 + lo][ib + hi * 4 + r]      = f2bf(o01[r] * ls0[r]);
            oS[h * 32 + lo][ib + 16 + hi * 4 + r]      = f2bf(o10[r] * ls1[r]);
            oS[h * 32 + 16 + lo][ib + 16 + hi * 4 + r] = f2bf(o11[r] * ls1[r]);
        }
    }
    __syncthreads();

    // ---- coalesced store: ao[ch][p0 + s] ----
    #pragma unroll
    for (int itr = 0; itr < 4; ++itr) {
        const int u = t + itr * 512;
        const int ch = u >> 4, seg = u & 15;
        *(uint4*)(ao + (size_t)ch * SL + p0 + seg * 8) = *(const uint4*)&oS[ch][seg * 8];
    }
}

// ---------------------------------------------------------------------------
// ln_mid (LN1): x fp32 d-major + ao bf16 d-major -> o1b bf16 pos-major.
// ---------------------------------------------------------------------------
__global__ __launch_bounds__(256) void ln_mid(const float* __restrict__ in0,
                                              const u16* __restrict__ in1,
                                              const float* __restrict__ g,
                                              const float* __restrict__ be,
                                              u16* __restrict__ outp) {
    __shared__ float val[128][69];
    __shared__ float redS[4][72];
    __shared__ float redQ[4][72];
    __shared__ float stat[64][2];
    __shared__ float gs[128], bes[128];
    const int bid = blockIdx.x;
    const int r0 = (bid / 16) * 4;
    const int c0 = (bid % 16) * 16;
    const int t = threadIdx.x;
    const int pos = t & 63, q = t >> 6;
    const size_t gp = (size_t)(r0 + (pos >> 4)) * 256 + c0 + (pos & 15);

    if (t < 128) { gs[t] = g[t]; bes[t] = be[t]; }
    float s = 0.f, ss = 0.f;
    #pragma unroll 4
    for (int dd = 0; dd < 32; ++dd) {
        const int d = q * 32 + dd;
        float v = in0[(size_t)d * SL + gp] + bf2f(in1[(size_t)d * SL + gp]);
        val[d][pos] = v;
        s += v; ss += v * v;
    }
    redS[q][pos] = s;
    redQ[q][pos] = ss;
    __syncthreads();
    if (t < 64) {
        const float S  = redS[0][t] + redS[1][t] + redS[2][t] + redS[3][t];
        const float SS = redQ[0][t] + redQ[1][t] + redQ[2][t] + redQ[3][t];
        const float mean = S * (1.f / 128.f);
        const float var  = SS * (1.f / 128.f) - mean * mean;
        stat[t][0] = mean;
        stat[t][1] = rsqrtf(var + EPS_LN);
    }
    __syncthreads();

    {
        const int pr = pos >> 4, pc = pos & 15;
        const size_t pp = (size_t)(c0 + pc) * 128 + r0 + pr;   // p' = l*128+s
        const float mean = stat[pos][0], rstd = stat[pos][1];
        union { uint4 v[4]; u16 u[32]; } O;
        #pragma unroll
        for (int dd = 0; dd < 32; ++dd) {
            const int d = q * 32 + dd;
            O.u[dd] = f2bf((val[d][pos] - mean) * rstd * gs[d] + bes[d]);
        }
        uint4* dst = (uint4*)(outp + pp * 128 + q * 32);
        #pragma unroll
        for (int k = 0; k < 4; ++k) dst[k] = O.v[k];
    }
}

// ---------------------------------------------------------------------------
// ln_out (LN2): o1b pos-major + ao ch-major over p' -> final fp32 d-major.
// ---------------------------------------------------------------------------
__global__ __launch_bounds__(256) void ln_out(const u16* __restrict__ in0,
                                              const u16* __restrict__ in1,
                                              const float* __restrict__ g,
                                              const float* __restrict__ be,
                                              float* __restrict__ outp) {
    __shared__ float val[128][69];
    __shared__ float redS[4][72];
    __shared__ float redQ[4][72];
    __shared__ float stat[64][2];
    const int bid = blockIdx.x;
    const int r0 = (bid / 8) * 4;
    const int c0 = (bid % 8) * 16;
    const int t = threadIdx.x;
    const int pos = t & 63, q = t >> 6;
    const size_t gp = (size_t)(r0 + (pos >> 4)) * 128 + c0 + (pos & 15);

    float s = 0.f, ss = 0.f;
    {
        union { uint4 v[4]; u16 u[32]; } A;
        const uint4* src = (const uint4*)(in0 + gp * 128 + q * 32);
        #pragma unroll
        for (int k = 0; k < 4; ++k) A.v[k] = src[k];
        #pragma unroll 4
        for (int dd = 0; dd < 32; ++dd) {
            const int d = q * 32 + dd;
            float v = bf2f(A.u[dd]) + bf2f(in1[(size_t)d * SL + gp]);
            val[d][pos] = v;
            s += v; ss += v * v;
        }
    }
    redS[q][pos] = s;
    redQ[q][pos] = ss;
    __syncthreads();
    if (t < 64) {
        const float S  = redS[0][t] + redS[1][t] + redS[2][t] + redS[3][t];
        const float SS = redQ[0][t] + redQ[1][t] + redQ[2][t] + redQ[3][t];
        const float mean = S * (1.f / 128.f);
        const float var  = SS * (1.f / 128.f) - mean * mean;
        stat[t][0] = mean;
        stat[t][1] = rsqrtf(var + EPS_LN);
    }
    __syncthreads();

    {
        const int d = t >> 1;
        const int ch = (t & 1) * 8;
        const float gd = g[d], bd = be[d];
        #pragma unroll
        for (int cc = 0; cc < 8; ++cc) {
            const int c = ch + cc;
            float ov[4];
            #pragma unroll
            for (int r = 0; r < 4; ++r) {
                const int p = r * 16 + c;
                ov[r] = (val[d][p] - stat[p][0]) * stat[p][1] * gd + bd;
            }
            float* dst = outp + (size_t)d * SL + (c0 + c) * 256 + r0;
            *(float4*)dst = make_float4(ov[0], ov[1], ov[2], ov[3]);
        }
    }
}

// ---------------------------------------------------------------------------
extern "C" void kernel_launch(void* const* d_in, const int* in_sizes, int n_in,
                              void* d_out, int out_size, void* d_ws, size_t ws_size,
                              hipStream_t stream) {
    const float* x     = (const float*)d_in[0];
    const float* w_row = (const float*)d_in[1];
    const float* b_row = (const float*)d_in[2];
    const float* w_col = (const float*)d_in[3];
    const float* b_col = (const float*)d_in[4];
    const float* g1    = (const float*)d_in[5];
    const float* be1   = (const float*)d_in[6];
    const float* g2    = (const float*)d_in[7];
    const float* be2   = (const float*)d_in[8];
    float* out = (float*)d_out;

    // ws: qT 8MB | kT 8MB | vb 8MB | ao 8MB | o1b 8MB | wrb 96KB | wcb 96KB
    char* base = (char*)d_ws;
    u16* qTb = (u16*)base;                        base += (size_t)128 * SL * 2;
    u16* kTb = (u16*)base;                        base += (size_t)128 * SL * 2;
    u16* vbb = (u16*)base;                        base += (size_t)128 * SL * 2;
    u16* ao16 = (u16*)base;                       base += (size_t)128 * SL * 2;
    u16* o1b  = (u16*)base;                       base += (size_t)128 * SL * 2;
    u16* wrb  = (u16*)base;                       base += (size_t)384 * 128 * 2;
    u16* wcb  = (u16*)base;

    wcast_kernel<<<48, 256, 0, stream>>>(w_row, w_col, wrb, wcb);
    qkv_mfma<<<512, 512, 0, stream>>>(x, wrb, b_row, qTb, kTb, vbb);
    attn_kernel<256, 512><<<512, 512, 0, stream>>>(qTb, kTb, vbb, ao16);
    ln_mid<<<512, 256, 0, stream>>>(x, ao16, g1, be1, o1b);
    qkv_attn2<<<256, 512, 0, stream>>>(o1b, wcb, b_col, ao16);
    ln_out<<<512, 256, 0, stream>>>(o1b, ao16, g2, be2, out);
}